// Round 1
// baseline (347.323 us; speedup 1.0000x reference)
//
#include <hip/hip_runtime.h>

typedef _Float16 half8 __attribute__((ext_vector_type(8)));
typedef float f32x4 __attribute__((ext_vector_type(4)));

union Frag { half8 v; unsigned int u32[4]; uint4 u4; };
union Pack4 { _Float16 h[4]; unsigned int u[2]; };

constexpr int S = 4096;
constexpr int D = 64;
constexpr int NB = 16;
constexpr int LTS = 72;   // f16 LDS row stride (dword stride 36): balanced-bank b128 frag reads

__device__ __forceinline__ float ex2(float x) {
#if __has_builtin(__builtin_amdgcn_exp2f)
    return __builtin_amdgcn_exp2f(x);   // raw v_exp_f32: no libm range fixups
#else
    return exp2f(x);
#endif
}

// ---- fused prepass: K f32 -> f16 row-major; V f32 -> f16 transposed [b][d][s] ----
__global__ __launch_bounds__(256)
void prep_kernel(const float* __restrict__ K, const float* __restrict__ V,
                 _Float16* __restrict__ K16, _Float16* __restrict__ VT) {
    __shared__ float tl[64 * 66];
    const int tid = threadIdx.x;
    const int s0 = blockIdx.x * 64;
    const int b  = blockIdx.y;
    const float* Kb = K + ((size_t)b * S + s0) * D;
    const float* Vb = V + ((size_t)b * S + s0) * D;
    _Float16* K16b = K16 + ((size_t)b * S + s0) * D;

    #pragma unroll
    for (int i = 0; i < 2; ++i) {
        int e8 = tid + 256 * i;
        float4 a = ((const float4*)Kb)[2 * e8];
        float4 c = ((const float4*)Kb)[2 * e8 + 1];
        Frag f;
        f.v[0]=(_Float16)a.x; f.v[1]=(_Float16)a.y; f.v[2]=(_Float16)a.z; f.v[3]=(_Float16)a.w;
        f.v[4]=(_Float16)c.x; f.v[5]=(_Float16)c.y; f.v[6]=(_Float16)c.z; f.v[7]=(_Float16)c.w;
        ((uint4*)K16b)[e8] = f.u4;
    }
    #pragma unroll
    for (int i = 0; i < 4; ++i) {
        int fi = tid + 256 * i;
        int r = fi >> 4, c4 = (fi & 15) << 2;
        float4 v = *(const float4*)(Vb + (size_t)r * D + c4);
        float2* p = (float2*)&tl[r * 66 + c4];
        p[0] = make_float2(v.x, v.y);
        p[1] = make_float2(v.z, v.w);
    }
    __syncthreads();
    _Float16* VTb = VT + (size_t)b * D * S;
    #pragma unroll
    for (int i = 0; i < 2; ++i) {
        int fi = tid + 256 * i;
        int d = fi >> 3, s8 = (fi & 7) << 3;
        Frag f;
        #pragma unroll
        for (int j = 0; j < 8; ++j) f.v[j] = (_Float16)tl[(s8 + j) * 66 + d];
        *(uint4*)(VTb + (size_t)d * S + s0 + s8) = f.u4;
    }
}

// ============ hot loop: 32 q-rows/wave (2 q-groups), 128 q-rows/block ============
// S^T = K @ Q^T operand swap. P never touches LDS: after exp+f16-pack, the
// C-layout (lane: key=quad*4+r, q=ln) is block-transposed to the PV A-frag
// layout (lane: q=ln, key=quad*8+j) with v_permlane32/16_swap_b32:
//   swap32(w_ct0, w_ct1): dst_hi<->src_lo => lanes 0-31 hold ct0 data, 32-63 ct1
//   swap16(x, y): per 32-half, 16-groups qs1<->qs2 => x = A0/A1 words, y = A2/A3
// LDS drops 36.9KB -> 18.4KB: 8 blocks/CU possible (grid = exactly 8/CU).
template <int SPLIT>
__device__ __forceinline__
void fattn_body(const float* __restrict__ Q, const _Float16* __restrict__ K16,
                const _Float16* __restrict__ VT16, float* __restrict__ Out,
                _Float16* __restrict__ OP, float* __restrict__ LP,
                int b, int J, int t0, int t1, int h) {
    __shared__ __align__(16) _Float16 kt[64 * LTS];        // 9.2 KB  K tile [key][d]
    __shared__ __align__(16) _Float16 vt[64 * LTS];        // 9.2 KB  V^T tile [d][key]

    const int tid  = threadIdx.x;
    const int lane = tid & 63;
    const int wave = tid >> 6;
    const int ln   = lane & 15;
    const int quad = lane >> 4;

    const float* Qb = Q + (size_t)b * S * D;
    const _Float16* Kb = K16 + (size_t)b * S * D;
    const _Float16* VTb = VT16 + (size_t)b * D * S;

    const float qscale = 0.125f * 1.44269504088896340736f;  // 1/sqrt(64) * log2(e)
    const int qrow_base = J * 128 + wave * 32;
    const int tw = (qrow_base + 31) >> 6;     // wave's diagonal tile; t>tw fully masked (exp->0)

    // Q fragments qf[qg][ks]: MFMA *B* operand (n=q=ln, k=d=quad*8+j)
    Frag qf[2][2];
    #pragma unroll
    for (int qg = 0; qg < 2; ++qg) {
        const float* qrow = Qb + (size_t)(qrow_base + qg * 16 + ln) * D + quad * 8;
        #pragma unroll
        for (int ks = 0; ks < 2; ++ks) {
            float4 a = *(const float4*)(qrow + ks * 32);
            float4 c = *(const float4*)(qrow + ks * 32 + 4);
            Frag f;
            f.v[0]=(_Float16)(a.x*qscale); f.v[1]=(_Float16)(a.y*qscale);
            f.v[2]=(_Float16)(a.z*qscale); f.v[3]=(_Float16)(a.w*qscale);
            f.v[4]=(_Float16)(c.x*qscale); f.v[5]=(_Float16)(c.y*qscale);
            f.v[6]=(_Float16)(c.z*qscale); f.v[7]=(_Float16)(c.w*qscale);
            qf[qg][ks] = f;
        }
    }

    f32x4 o[2][4] = {};
    float l_acc[2] = {0.f, 0.f};

    for (int t = t0; t < t1; ++t) {
        const int k0 = t * 64;
        __syncthreads();

        #pragma unroll
        for (int i = 0; i < 2; ++i) {
            int fi = tid + 256 * i;
            int r = fi >> 3, c8 = (fi & 7) << 3;
            uint4 kk = *(const uint4*)(Kb + (size_t)(k0 + r) * D + c8);
            uint4 vv = *(const uint4*)(VTb + (size_t)r * S + k0 + c8);
            *(uint4*)(kt + r * LTS + c8) = kk;
            *(uint4*)(vt + r * LTS + c8) = vv;
        }
        __syncthreads();

        // ---- per 32-key half: S^T = K @ Q^T, exp, in-register transpose, PV ----
        #pragma unroll
        for (int ks = 0; ks < 2; ++ks) {
            unsigned w[2][2][2];   // [qg][ct_local][word]; word = key pair (even,odd)
            #pragma unroll
            for (int cl = 0; cl < 2; ++cl) {
                const int ct = ks * 2 + cl;
                Frag kf0, kf1;
                kf0.u4 = *(const uint4*)(kt + (ct * 16 + ln) * LTS + quad * 8);
                kf1.u4 = *(const uint4*)(kt + (ct * 16 + ln) * LTS + 32 + quad * 8);
                #pragma unroll
                for (int qg = 0; qg < 2; ++qg) {
                    f32x4 acc = {0.f, 0.f, 0.f, 0.f};
                    acc = __builtin_amdgcn_mfma_f32_16x16x32_f16(kf0.v, qf[qg][0].v, acc, 0, 0, 0);
                    acc = __builtin_amdgcn_mfma_f32_16x16x32_f16(kf1.v, qf[qg][1].v, acc, 0, 0, 0);
                    if (t >= tw) {   // diagonal (partial) or beyond (fully masked -> exp=0)
                        int keyb = k0 + ct * 16 + quad * 4;
                        int qrow = qrow_base + qg * 16 + ln;
                        #pragma unroll
                        for (int r = 0; r < 4; ++r)
                            if (keyb + r > qrow) acc[r] = -1e30f;
                    }
                    float p0 = ex2(acc[0]), p1 = ex2(acc[1]);
                    float p2 = ex2(acc[2]), p3 = ex2(acc[3]);
                    l_acc[qg] += (p0 + p1) + (p2 + p3);
                    Pack4 pk;            // RTNE f16, same numerics as previous version
                    pk.h[0] = (_Float16)p0; pk.h[1] = (_Float16)p1;
                    pk.h[2] = (_Float16)p2; pk.h[3] = (_Float16)p3;
                    w[qg][cl][0] = pk.u[0];
                    w[qg][cl][1] = pk.u[1];
                }
            }

            // in-register block transpose -> PV A-frags (no LDS round-trip)
            Frag pf[2];
            #pragma unroll
            for (int qg = 0; qg < 2; ++qg) {
                unsigned x0 = w[qg][0][0], y0 = w[qg][1][0];
                unsigned x1 = w[qg][0][1], y1 = w[qg][1][1];
                asm("v_permlane32_swap_b32 %0, %1" : "+v"(x0), "+v"(y0));
                asm("v_permlane32_swap_b32 %0, %1" : "+v"(x1), "+v"(y1));
                asm("v_permlane16_swap_b32 %0, %1" : "+v"(x0), "+v"(y0));
                asm("v_permlane16_swap_b32 %0, %1" : "+v"(x1), "+v"(y1));
                pf[qg].u32[0] = x0; pf[qg].u32[1] = x1;   // A0,A1: keys quad*8+0..3
                pf[qg].u32[2] = y0; pf[qg].u32[3] = y1;   // A2,A3: keys quad*8+4..7
            }

            // ---- O += P @ V for this half; vf reused across both q-groups ----
            #pragma unroll
            for (int sub = 0; sub < 4; ++sub) {
                Frag vf;
                vf.u4 = *(const uint4*)(vt + (sub * 16 + ln) * LTS + ks * 32 + quad * 8);
                #pragma unroll
                for (int qg = 0; qg < 2; ++qg)
                    o[qg][sub] = __builtin_amdgcn_mfma_f32_16x16x32_f16(pf[qg].v, vf.v, o[qg][sub], 0, 0, 0);
            }
        }
    }

    // full denom per q (sum 4 quad-partials); lane ln holds denom of q = qg*16+ln
    float lf[2];
    #pragma unroll
    for (int qg = 0; qg < 2; ++qg) {
        float x = l_acc[qg];
        x += __shfl_xor(x, 16, 64);
        x += __shfl_xor(x, 32, 64);
        lf[qg] = x;
    }

    if (SPLIT) {
        // normalized f16 partial: Ohat = O/l (|Ohat| <= max|v|, f16-safe); merge = sum(l*Ohat)/sum(l)
        _Float16* OPb = OP + (size_t)(((b * 32 + J) * 4 + h)) * 8192;
        float* LPb = LP + (size_t)(((b * 32 + J) * 4 + h)) * 128;
        #pragma unroll
        for (int qg = 0; qg < 2; ++qg) {
            if (quad == 0) LPb[wave * 32 + qg * 16 + ln] = lf[qg];
            #pragma unroll
            for (int r = 0; r < 4; ++r) {
                float lrow = __shfl(lf[qg], quad * 4 + r, 64);
                float inv = (lrow > 0.f) ? (1.0f / lrow) : 0.f;  // guard: fully-masked/empty chunk
                #pragma unroll
                for (int sub = 0; sub < 4; ++sub)
                    OPb[(wave * 32 + qg * 16 + quad * 4 + r) * 64 + sub * 16 + ln] =
                        (_Float16)(o[qg][sub][r] * inv);
            }
        }
    } else {
        float* Ob = Out + (size_t)b * S * D;
        #pragma unroll
        for (int qg = 0; qg < 2; ++qg) {
            #pragma unroll
            for (int r = 0; r < 4; ++r) {
                float lrow = __shfl(lf[qg], quad * 4 + r, 64);
                float inv = 1.0f / lrow;
                #pragma unroll
                for (int sub = 0; sub < 4; ++sub)
                    Ob[(size_t)(qrow_base + qg * 16 + quad * 4 + r) * D + sub * 16 + ln] =
                        o[qg][sub][r] * inv;
            }
        }
    }
}

// split-K x4 over 128-q-row blocks: grid 2048 = 32 J x 4 quarters x 16 batches, LPT.
// LDS 18.4KB => up to 8 blocks/CU: whole grid co-resident.
// launch_bounds min-waves=6: no-spill VGPR cap (85); actual <=64 still yields 8 blk/CU.
__global__ __launch_bounds__(256, 6)
void fattn_split_kernel(const float* __restrict__ Q, const _Float16* __restrict__ K16,
                        const _Float16* __restrict__ VT16,
                        _Float16* __restrict__ OP, float* __restrict__ LP) {
    const int bx = blockIdx.x;
    const int J = 31 - (bx >> 6);
    const int h = (bx >> 4) & 3;
    const int b = bx & 15;
    const int n  = 2 * J + 2;
    const int t0 = (h * n) >> 2;
    const int t1 = ((h + 1) * n) >> 2;
    fattn_body<1>(Q, K16, VT16, nullptr, OP, LP, b, J, t0, t1, h);
}

// fallback (ws too small): full range, direct store
__global__ __launch_bounds__(256, 6)
void fattn_kernel(const float* __restrict__ Q, const _Float16* __restrict__ K16,
                  const _Float16* __restrict__ VT16, float* __restrict__ Out) {
    const int bx = blockIdx.x;
    const int J = 31 - (bx >> 4);
    const int b = bx & 15;
    fattn_body<0>(Q, K16, VT16, Out, nullptr, nullptr, b, J, 0, 2 * J + 2, 0);
}

// merge: Out = sum_h(l_h * Ohat_h) / sum_h(l_h); one block per (b, J) tile of 128 rows
__global__ __launch_bounds__(256)
void reduce_kernel(const _Float16* __restrict__ OP, const float* __restrict__ LP,
                   float* __restrict__ Out) {
    const int rb = blockIdx.x;
    const int b  = rb & 15;
    const int J  = rb >> 4;
    const int tid = threadIdx.x;
    const _Float16* p = OP + (size_t)(b * 32 + J) * 4 * 8192;
    const float* l = LP + (size_t)(b * 32 + J) * 4 * 128;
    float* Ob = Out + (size_t)b * S * D + (size_t)J * 8192;
    #pragma unroll
    for (int i = 0; i < 4; ++i) {
        int e8 = tid + 256 * i;                 // half8 group index within 1024
        int q  = e8 >> 3;                       // q-row 0..127
        float lw[4], lsum = 0.f;
        #pragma unroll
        for (int hh = 0; hh < 4; ++hh) { lw[hh] = l[hh * 128 + q]; lsum += lw[hh]; }
        float inv = 1.0f / lsum;
        float acc[8] = {};
        #pragma unroll
        for (int hh = 0; hh < 4; ++hh) {
            half8 v = *(const half8*)(p + (size_t)hh * 8192 + e8 * 8);
            #pragma unroll
            for (int j = 0; j < 8; ++j) acc[j] += lw[hh] * (float)v[j];
        }
        float4 r0, r1;
        r0.x = acc[0]*inv; r0.y = acc[1]*inv; r0.z = acc[2]*inv; r0.w = acc[3]*inv;
        r1.x = acc[4]*inv; r1.y = acc[5]*inv; r1.z = acc[6]*inv; r1.w = acc[7]*inv;
        ((float4*)Ob)[2 * e8]     = r0;
        ((float4*)Ob)[2 * e8 + 1] = r1;
    }
}

extern "C" void kernel_launch(void* const* d_in, const int* in_sizes, int n_in,
                              void* d_out, int out_size, void* d_ws, size_t ws_size,
                              hipStream_t stream) {
    const float* Q = (const float*)d_in[0];
    const float* K = (const float*)d_in[1];
    const float* V = (const float*)d_in[2];
    float* O = (float*)d_out;

    const size_t prepBytes = (size_t)NB * S * D * 2;            // 8.39 MB each
    _Float16* K16  = (_Float16*)d_ws;
    _Float16* VT16 = (_Float16*)((char*)d_ws + prepBytes);

    const size_t opOff = 2 * prepBytes;                         // 16.78 MB
    const size_t opBytes = (size_t)NB * 32 * 4 * 8192 * 2;      // 33.55 MB (f16 partials)
    const size_t lpOff = opOff + opBytes;
    const size_t lpBytes = (size_t)NB * 32 * 4 * 128 * 4;       // 1.05 MB
    const size_t need = lpOff + lpBytes;                        // ~51.4 MB

    hipLaunchKernelGGL(prep_kernel, dim3(S / 64, NB), dim3(256), 0, stream, K, V, K16, VT16);

    if (ws_size >= need) {
        _Float16* OP = (_Float16*)((char*)d_ws + opOff);
        float* LP = (float*)((char*)d_ws + lpOff);
        hipLaunchKernelGGL(fattn_split_kernel, dim3(128 * NB), dim3(256), 0, stream,
                           Q, K16, VT16, OP, LP);
        hipLaunchKernelGGL(reduce_kernel, dim3(32 * NB), dim3(256), 0, stream, OP, LP, O);
    } else {
        hipLaunchKernelGGL(fattn_kernel, dim3(32 * NB), dim3(256), 0, stream, Q, K16, VT16, O);
    }
}

// Round 3
// 187.556 us; speedup vs baseline: 1.8518x; 1.8518x over previous
//
#include <hip/hip_runtime.h>

typedef _Float16 half8 __attribute__((ext_vector_type(8)));
typedef float f32x4 __attribute__((ext_vector_type(4)));
typedef unsigned int uint32x2 __attribute__((ext_vector_type(2)));

union Frag { half8 v; unsigned int u32[4]; uint4 u4; };
union Pack4 { _Float16 h[4]; unsigned int u[2]; };

constexpr int S = 4096;
constexpr int D = 64;
constexpr int NB = 16;
constexpr int LTS = 72;   // f16 LDS row stride (dword stride 36): balanced-bank b128 frag reads

__device__ __forceinline__ float ex2(float x) {
#if __has_builtin(__builtin_amdgcn_exp2f)
    return __builtin_amdgcn_exp2f(x);   // raw v_exp_f32: no libm range fixups
#else
    return exp2f(x);
#endif
}

// ---- fused prepass: K f32 -> f16 row-major; V f32 -> f16 transposed [b][d][s] ----
__global__ __launch_bounds__(256)
void prep_kernel(const float* __restrict__ K, const float* __restrict__ V,
                 _Float16* __restrict__ K16, _Float16* __restrict__ VT) {
    __shared__ float tl[64 * 66];
    const int tid = threadIdx.x;
    const int s0 = blockIdx.x * 64;
    const int b  = blockIdx.y;
    const float* Kb = K + ((size_t)b * S + s0) * D;
    const float* Vb = V + ((size_t)b * S + s0) * D;
    _Float16* K16b = K16 + ((size_t)b * S + s0) * D;

    #pragma unroll
    for (int i = 0; i < 2; ++i) {
        int e8 = tid + 256 * i;
        float4 a = ((const float4*)Kb)[2 * e8];
        float4 c = ((const float4*)Kb)[2 * e8 + 1];
        Frag f;
        f.v[0]=(_Float16)a.x; f.v[1]=(_Float16)a.y; f.v[2]=(_Float16)a.z; f.v[3]=(_Float16)a.w;
        f.v[4]=(_Float16)c.x; f.v[5]=(_Float16)c.y; f.v[6]=(_Float16)c.z; f.v[7]=(_Float16)c.w;
        ((uint4*)K16b)[e8] = f.u4;
    }
    #pragma unroll
    for (int i = 0; i < 4; ++i) {
        int fi = tid + 256 * i;
        int r = fi >> 4, c4 = (fi & 15) << 2;
        float4 v = *(const float4*)(Vb + (size_t)r * D + c4);
        float2* p = (float2*)&tl[r * 66 + c4];
        p[0] = make_float2(v.x, v.y);
        p[1] = make_float2(v.z, v.w);
    }
    __syncthreads();
    _Float16* VTb = VT + (size_t)b * D * S;
    #pragma unroll
    for (int i = 0; i < 2; ++i) {
        int fi = tid + 256 * i;
        int d = fi >> 3, s8 = (fi & 7) << 3;
        Frag f;
        #pragma unroll
        for (int j = 0; j < 8; ++j) f.v[j] = (_Float16)tl[(s8 + j) * 66 + d];
        *(uint4*)(VTb + (size_t)d * S + s0 + s8) = f.u4;
    }
}

// ============ hot loop: 32 q-rows/wave (2 q-groups), 128 q-rows/block ============
// S^T = K @ Q^T operand swap. P never touches LDS: after exp+f16-pack, the
// C-layout (lane: key=quad*4+r, q=ln) is block-transposed to the PV A-frag
// layout (lane: q=ln, key=quad*8+j) with permlane32/16_swap.
// MUST use the builtins, not raw asm: R2 showed raw-asm permlane is schedule-
// sensitive (gfx950 wait-state hazards at the asm boundary are not inserted by
// the compiler for opaque asm; R1's spill code masked them, R2's tight schedule
// exposed them -> absmax 0.74). Builtins let the hazard recognizer do its job.
// LDS 18.4KB; launch_bounds(256,4) — (256,6) made the allocator pick a 40-VGPR
// tier and spill the accumulators to scratch (R1: 224MB scratch writes, 3.1x dur).
template <int SPLIT>
__device__ __forceinline__
void fattn_body(const float* __restrict__ Q, const _Float16* __restrict__ K16,
                const _Float16* __restrict__ VT16, float* __restrict__ Out,
                _Float16* __restrict__ OP, float* __restrict__ LP,
                int b, int J, int t0, int t1, int h) {
    __shared__ __align__(16) _Float16 kt[64 * LTS];        // 9.2 KB  K tile [key][d]
    __shared__ __align__(16) _Float16 vt[64 * LTS];        // 9.2 KB  V^T tile [d][key]

    const int tid  = threadIdx.x;
    const int lane = tid & 63;
    const int wave = tid >> 6;
    const int ln   = lane & 15;
    const int quad = lane >> 4;

    const float* Qb = Q + (size_t)b * S * D;
    const _Float16* Kb = K16 + (size_t)b * S * D;
    const _Float16* VTb = VT16 + (size_t)b * D * S;

    const float qscale = 0.125f * 1.44269504088896340736f;  // 1/sqrt(64) * log2(e)
    const int qrow_base = J * 128 + wave * 32;
    const int tw = (qrow_base + 31) >> 6;     // wave's diagonal tile; t>tw fully masked (exp->0)

    // Q fragments qf[qg][ks]: MFMA *B* operand (n=q=ln, k=d=quad*8+j)
    Frag qf[2][2];
    #pragma unroll
    for (int qg = 0; qg < 2; ++qg) {
        const float* qrow = Qb + (size_t)(qrow_base + qg * 16 + ln) * D + quad * 8;
        #pragma unroll
        for (int ks = 0; ks < 2; ++ks) {
            float4 a = *(const float4*)(qrow + ks * 32);
            float4 c = *(const float4*)(qrow + ks * 32 + 4);
            Frag f;
            f.v[0]=(_Float16)(a.x*qscale); f.v[1]=(_Float16)(a.y*qscale);
            f.v[2]=(_Float16)(a.z*qscale); f.v[3]=(_Float16)(a.w*qscale);
            f.v[4]=(_Float16)(c.x*qscale); f.v[5]=(_Float16)(c.y*qscale);
            f.v[6]=(_Float16)(c.z*qscale); f.v[7]=(_Float16)(c.w*qscale);
            qf[qg][ks] = f;
        }
    }

    f32x4 o[2][4] = {};
    float l_acc[2] = {0.f, 0.f};

    for (int t = t0; t < t1; ++t) {
        const int k0 = t * 64;
        __syncthreads();

        #pragma unroll
        for (int i = 0; i < 2; ++i) {
            int fi = tid + 256 * i;
            int r = fi >> 3, c8 = (fi & 7) << 3;
            uint4 kk = *(const uint4*)(Kb + (size_t)(k0 + r) * D + c8);
            uint4 vv = *(const uint4*)(VTb + (size_t)r * S + k0 + c8);
            *(uint4*)(kt + r * LTS + c8) = kk;
            *(uint4*)(vt + r * LTS + c8) = vv;
        }
        __syncthreads();

        // ---- per 32-key half: S^T = K @ Q^T, exp, in-register transpose, PV ----
        #pragma unroll
        for (int ks = 0; ks < 2; ++ks) {
            unsigned w[2][2][2];   // [qg][ct_local][word]; word = key pair (even,odd)
            #pragma unroll
            for (int cl = 0; cl < 2; ++cl) {
                const int ct = ks * 2 + cl;
                Frag kf0, kf1;
                kf0.u4 = *(const uint4*)(kt + (ct * 16 + ln) * LTS + quad * 8);
                kf1.u4 = *(const uint4*)(kt + (ct * 16 + ln) * LTS + 32 + quad * 8);
                #pragma unroll
                for (int qg = 0; qg < 2; ++qg) {
                    f32x4 acc = {0.f, 0.f, 0.f, 0.f};
                    acc = __builtin_amdgcn_mfma_f32_16x16x32_f16(kf0.v, qf[qg][0].v, acc, 0, 0, 0);
                    acc = __builtin_amdgcn_mfma_f32_16x16x32_f16(kf1.v, qf[qg][1].v, acc, 0, 0, 0);
                    if (t >= tw) {   // diagonal (partial) or beyond (fully masked -> exp=0)
                        int keyb = k0 + ct * 16 + quad * 4;
                        int qrow = qrow_base + qg * 16 + ln;
                        #pragma unroll
                        for (int r = 0; r < 4; ++r)
                            if (keyb + r > qrow) acc[r] = -1e30f;
                    }
                    float p0 = ex2(acc[0]), p1 = ex2(acc[1]);
                    float p2 = ex2(acc[2]), p3 = ex2(acc[3]);
                    l_acc[qg] += (p0 + p1) + (p2 + p3);
                    Pack4 pk;            // RTNE f16, same numerics as previous version
                    pk.h[0] = (_Float16)p0; pk.h[1] = (_Float16)p1;
                    pk.h[2] = (_Float16)p2; pk.h[3] = (_Float16)p3;
                    w[qg][cl][0] = pk.u[0];
                    w[qg][cl][1] = pk.u[1];
                }
            }

            // in-register block transpose -> PV A-frags (no LDS round-trip)
            Frag pf[2];
            #pragma unroll
            for (int qg = 0; qg < 2; ++qg) {
                unsigned x0 = w[qg][0][0], y0 = w[qg][1][0];
                unsigned x1 = w[qg][0][1], y1 = w[qg][1][1];
#if __has_builtin(__builtin_amdgcn_permlane32_swap) && __has_builtin(__builtin_amdgcn_permlane16_swap)
                uint32x2 r;
                r = __builtin_amdgcn_permlane32_swap(x0, y0, false, false); x0 = r[0]; y0 = r[1];
                r = __builtin_amdgcn_permlane32_swap(x1, y1, false, false); x1 = r[0]; y1 = r[1];
                r = __builtin_amdgcn_permlane16_swap(x0, y0, false, false); x0 = r[0]; y0 = r[1];
                r = __builtin_amdgcn_permlane16_swap(x1, y1, false, false); x1 = r[0]; y1 = r[1];
#else
                asm volatile("s_nop 1\n\tv_permlane32_swap_b32 %0, %1\n\ts_nop 1"
                             : "+v"(x0), "+v"(y0));
                asm volatile("v_permlane32_swap_b32 %0, %1\n\ts_nop 1"
                             : "+v"(x1), "+v"(y1));
                asm volatile("v_permlane16_swap_b32 %0, %1\n\ts_nop 1"
                             : "+v"(x0), "+v"(y0));
                asm volatile("v_permlane16_swap_b32 %0, %1\n\ts_nop 1"
                             : "+v"(x1), "+v"(y1));
#endif
                pf[qg].u32[0] = x0; pf[qg].u32[1] = x1;   // A0,A1: keys quad*8+0..3
                pf[qg].u32[2] = y0; pf[qg].u32[3] = y1;   // A2,A3: keys quad*8+4..7
            }

            // ---- O += P @ V for this half; vf reused across both q-groups ----
            #pragma unroll
            for (int sub = 0; sub < 4; ++sub) {
                Frag vf;
                vf.u4 = *(const uint4*)(vt + (sub * 16 + ln) * LTS + ks * 32 + quad * 8);
                #pragma unroll
                for (int qg = 0; qg < 2; ++qg)
                    o[qg][sub] = __builtin_amdgcn_mfma_f32_16x16x32_f16(pf[qg].v, vf.v, o[qg][sub], 0, 0, 0);
            }
        }
    }

    // full denom per q (sum 4 quad-partials); lane ln holds denom of q = qg*16+ln
    float lf[2];
    #pragma unroll
    for (int qg = 0; qg < 2; ++qg) {
        float x = l_acc[qg];
        x += __shfl_xor(x, 16, 64);
        x += __shfl_xor(x, 32, 64);
        lf[qg] = x;
    }

    if (SPLIT) {
        // normalized f16 partial: Ohat = O/l (|Ohat| <= max|v|, f16-safe); merge = sum(l*Ohat)/sum(l)
        _Float16* OPb = OP + (size_t)(((b * 32 + J) * 4 + h)) * 8192;
        float* LPb = LP + (size_t)(((b * 32 + J) * 4 + h)) * 128;
        #pragma unroll
        for (int qg = 0; qg < 2; ++qg) {
            if (quad == 0) LPb[wave * 32 + qg * 16 + ln] = lf[qg];
            #pragma unroll
            for (int r = 0; r < 4; ++r) {
                float lrow = __shfl(lf[qg], quad * 4 + r, 64);
                float inv = (lrow > 0.f) ? (1.0f / lrow) : 0.f;  // guard: fully-masked/empty chunk
                #pragma unroll
                for (int sub = 0; sub < 4; ++sub)
                    OPb[(wave * 32 + qg * 16 + quad * 4 + r) * 64 + sub * 16 + ln] =
                        (_Float16)(o[qg][sub][r] * inv);
            }
        }
    } else {
        float* Ob = Out + (size_t)b * S * D;
        #pragma unroll
        for (int qg = 0; qg < 2; ++qg) {
            #pragma unroll
            for (int r = 0; r < 4; ++r) {
                float lrow = __shfl(lf[qg], quad * 4 + r, 64);
                float inv = 1.0f / lrow;
                #pragma unroll
                for (int sub = 0; sub < 4; ++sub)
                    Ob[(size_t)(qrow_base + qg * 16 + quad * 4 + r) * D + sub * 16 + ln] =
                        o[qg][sub][r] * inv;
            }
        }
    }
}

// split-K x4 over 128-q-row blocks: grid 2048 = 32 J x 4 quarters x 16 batches, LPT.
__global__ __launch_bounds__(256, 4)
void fattn_split_kernel(const float* __restrict__ Q, const _Float16* __restrict__ K16,
                        const _Float16* __restrict__ VT16,
                        _Float16* __restrict__ OP, float* __restrict__ LP) {
    const int bx = blockIdx.x;
    const int J = 31 - (bx >> 6);
    const int h = (bx >> 4) & 3;
    const int b = bx & 15;
    const int n  = 2 * J + 2;
    const int t0 = (h * n) >> 2;
    const int t1 = ((h + 1) * n) >> 2;
    fattn_body<1>(Q, K16, VT16, nullptr, OP, LP, b, J, t0, t1, h);
}

// fallback (ws too small): full range, direct store
__global__ __launch_bounds__(256, 4)
void fattn_kernel(const float* __restrict__ Q, const _Float16* __restrict__ K16,
                  const _Float16* __restrict__ VT16, float* __restrict__ Out) {
    const int bx = blockIdx.x;
    const int J = 31 - (bx >> 4);
    const int b = bx & 15;
    fattn_body<0>(Q, K16, VT16, Out, nullptr, nullptr, b, J, 0, 2 * J + 2, 0);
}

// merge: Out = sum_h(l_h * Ohat_h) / sum_h(l_h); one block per (b, J) tile of 128 rows
__global__ __launch_bounds__(256)
void reduce_kernel(const _Float16* __restrict__ OP, const float* __restrict__ LP,
                   float* __restrict__ Out) {
    const int rb = blockIdx.x;
    const int b  = rb & 15;
    const int J  = rb >> 4;
    const int tid = threadIdx.x;
    const _Float16* p = OP + (size_t)(b * 32 + J) * 4 * 8192;
    const float* l = LP + (size_t)(b * 32 + J) * 4 * 128;
    float* Ob = Out + (size_t)b * S * D + (size_t)J * 8192;
    #pragma unroll
    for (int i = 0; i < 4; ++i) {
        int e8 = tid + 256 * i;                 // half8 group index within 1024
        int q  = e8 >> 3;                       // q-row 0..127
        float lw[4], lsum = 0.f;
        #pragma unroll
        for (int hh = 0; hh < 4; ++hh) { lw[hh] = l[hh * 128 + q]; lsum += lw[hh]; }
        float inv = 1.0f / lsum;
        float acc[8] = {};
        #pragma unroll
        for (int hh = 0; hh < 4; ++hh) {
            half8 v = *(const half8*)(p + (size_t)hh * 8192 + e8 * 8);
            #pragma unroll
            for (int j = 0; j < 8; ++j) acc[j] += lw[hh] * (float)v[j];
        }
        float4 r0, r1;
        r0.x = acc[0]*inv; r0.y = acc[1]*inv; r0.z = acc[2]*inv; r0.w = acc[3]*inv;
        r1.x = acc[4]*inv; r1.y = acc[5]*inv; r1.z = acc[6]*inv; r1.w = acc[7]*inv;
        ((float4*)Ob)[2 * e8]     = r0;
        ((float4*)Ob)[2 * e8 + 1] = r1;
    }
}

extern "C" void kernel_launch(void* const* d_in, const int* in_sizes, int n_in,
                              void* d_out, int out_size, void* d_ws, size_t ws_size,
                              hipStream_t stream) {
    const float* Q = (const float*)d_in[0];
    const float* K = (const float*)d_in[1];
    const float* V = (const float*)d_in[2];
    float* O = (float*)d_out;

    const size_t prepBytes = (size_t)NB * S * D * 2;            // 8.39 MB each
    _Float16* K16  = (_Float16*)d_ws;
    _Float16* VT16 = (_Float16*)((char*)d_ws + prepBytes);

    const size_t opOff = 2 * prepBytes;                         // 16.78 MB
    const size_t opBytes = (size_t)NB * 32 * 4 * 8192 * 2;      // 33.55 MB (f16 partials)
    const size_t lpOff = opOff + opBytes;
    const size_t lpBytes = (size_t)NB * 32 * 4 * 128 * 4;       // 1.05 MB
    const size_t need = lpOff + lpBytes;                        // ~51.4 MB

    hipLaunchKernelGGL(prep_kernel, dim3(S / 64, NB), dim3(256), 0, stream, K, V, K16, VT16);

    if (ws_size >= need) {
        _Float16* OP = (_Float16*)((char*)d_ws + opOff);
        float* LP = (float*)((char*)d_ws + lpOff);
        hipLaunchKernelGGL(fattn_split_kernel, dim3(128 * NB), dim3(256), 0, stream,
                           Q, K16, VT16, OP, LP);
        hipLaunchKernelGGL(reduce_kernel, dim3(32 * NB), dim3(256), 0, stream, OP, LP, O);
    } else {
        hipLaunchKernelGGL(fattn_kernel, dim3(32 * NB), dim3(256), 0, stream, Q, K16, VT16, O);
    }
}

// Round 5
// 186.585 us; speedup vs baseline: 1.8615x; 1.0052x over previous
//
#include <hip/hip_runtime.h>

typedef _Float16 half8 __attribute__((ext_vector_type(8)));
typedef __fp16 fp16x2 __attribute__((ext_vector_type(2)));
typedef float f32x4 __attribute__((ext_vector_type(4)));
typedef unsigned int uint32x2 __attribute__((ext_vector_type(2)));

union Frag { half8 v; unsigned int u32[4]; uint4 u4; };
union Pack4 { _Float16 h[4]; unsigned int u[2]; };
union H2U { fp16x2 h; unsigned int u; };

constexpr int S = 4096;
constexpr int D = 64;
constexpr int NB = 16;
constexpr int LTS = 72;   // f16 LDS row stride (dword stride 36): balanced-bank b128 frag reads

__device__ __forceinline__ float ex2(float x) {
#if __has_builtin(__builtin_amdgcn_exp2f)
    return __builtin_amdgcn_exp2f(x);   // raw v_exp_f32: no libm range fixups
#else
    return exp2f(x);
#endif
}

// ---- fused prepass: K f32 -> f16 row-major; V f32 -> f16 transposed [b][d][s] ----
__global__ __launch_bounds__(256)
void prep_kernel(const float* __restrict__ K, const float* __restrict__ V,
                 _Float16* __restrict__ K16, _Float16* __restrict__ VT) {
    __shared__ float tl[64 * 66];
    const int tid = threadIdx.x;
    const int s0 = blockIdx.x * 64;
    const int b  = blockIdx.y;
    const float* Kb = K + ((size_t)b * S + s0) * D;
    const float* Vb = V + ((size_t)b * S + s0) * D;
    _Float16* K16b = K16 + ((size_t)b * S + s0) * D;

    #pragma unroll
    for (int i = 0; i < 2; ++i) {
        int e8 = tid + 256 * i;
        float4 a = ((const float4*)Kb)[2 * e8];
        float4 c = ((const float4*)Kb)[2 * e8 + 1];
        Frag f;
        f.v[0]=(_Float16)a.x; f.v[1]=(_Float16)a.y; f.v[2]=(_Float16)a.z; f.v[3]=(_Float16)a.w;
        f.v[4]=(_Float16)c.x; f.v[5]=(_Float16)c.y; f.v[6]=(_Float16)c.z; f.v[7]=(_Float16)c.w;
        ((uint4*)K16b)[e8] = f.u4;
    }
    #pragma unroll
    for (int i = 0; i < 4; ++i) {
        int fi = tid + 256 * i;
        int r = fi >> 4, c4 = (fi & 15) << 2;
        float4 v = *(const float4*)(Vb + (size_t)r * D + c4);
        float2* p = (float2*)&tl[r * 66 + c4];
        p[0] = make_float2(v.x, v.y);
        p[1] = make_float2(v.z, v.w);
    }
    __syncthreads();
    _Float16* VTb = VT + (size_t)b * D * S;
    #pragma unroll
    for (int i = 0; i < 2; ++i) {
        int fi = tid + 256 * i;
        int d = fi >> 3, s8 = (fi & 7) << 3;
        Frag f;
        #pragma unroll
        for (int j = 0; j < 8; ++j) f.v[j] = (_Float16)tl[(s8 + j) * 66 + d];
        *(uint4*)(VTb + (size_t)d * S + s0 + s8) = f.u4;
    }
}

// ============ hot loop: 32 q-rows/wave (2 q-groups), 128 q-rows/block ============
// S^T = K @ Q^T operand swap. P never touches LDS: permlane32/16_swap builtins
// block-transpose the exp'd scores to PV A-frags in-register (R2 lesson: builtins,
// never raw asm — gfx950 permlane wait-state hazards aren't inserted around asm).
// T14 async-stage: tile t+1 global loads issued after the staging barrier, LDS
// write deferred to next iteration top — L2/HBM latency hides under compute.
// launch_bounds(256,4): (256,6) picked a 40-VGPR spill tier (R1: 224MB scratch).
template <int SPLIT>
__device__ __forceinline__
void fattn_body(const float* __restrict__ Q, const _Float16* __restrict__ K16,
                const _Float16* __restrict__ VT16, float* __restrict__ Out,
                _Float16* __restrict__ OP, float* __restrict__ LP,
                int b, int J, int t0, int t1, int h) {
    __shared__ __align__(16) _Float16 kt[64 * LTS];        // 9.2 KB  K tile [key][d]
    __shared__ __align__(16) _Float16 vt[64 * LTS];        // 9.2 KB  V^T tile [d][key]

    const int tid  = threadIdx.x;
    const int lane = tid & 63;
    const int wave = tid >> 6;
    const int ln   = lane & 15;
    const int quad = lane >> 4;

    const float* Qb = Q + (size_t)b * S * D;
    const _Float16* Kb = K16 + (size_t)b * S * D;
    const _Float16* VTb = VT16 + (size_t)b * D * S;

    const float qscale = 0.125f * 1.44269504088896340736f;  // 1/sqrt(64) * log2(e)
    const int qrow_base = J * 128 + wave * 32;
    const int tw = (qrow_base + 31) >> 6;     // wave's diagonal tile; t>tw fully masked (exp->0)

    // Q fragments qf[qg][ks]: MFMA *B* operand (n=q=ln, k=d=quad*8+j)
    Frag qf[2][2];
    #pragma unroll
    for (int qg = 0; qg < 2; ++qg) {
        const float* qrow = Qb + (size_t)(qrow_base + qg * 16 + ln) * D + quad * 8;
        #pragma unroll
        for (int ks = 0; ks < 2; ++ks) {
            float4 a = *(const float4*)(qrow + ks * 32);
            float4 c = *(const float4*)(qrow + ks * 32 + 4);
            Frag f;
            f.v[0]=(_Float16)(a.x*qscale); f.v[1]=(_Float16)(a.y*qscale);
            f.v[2]=(_Float16)(a.z*qscale); f.v[3]=(_Float16)(a.w*qscale);
            f.v[4]=(_Float16)(c.x*qscale); f.v[5]=(_Float16)(c.y*qscale);
            f.v[6]=(_Float16)(c.z*qscale); f.v[7]=(_Float16)(c.w*qscale);
            qf[qg][ks] = f;
        }
    }

    f32x4 o[2][4] = {};
    float l_acc[2] = {0.f, 0.f};

    // T14 prefetch registers: tile data for the NEXT staging write (16 VGPRs)
    const int r0_ = tid >> 3,         c8_0 = (tid & 7) << 3;
    const int r1_ = (tid + 256) >> 3, c8_1 = ((tid + 256) & 7) << 3;
    uint4 pk0, pk1, pv0, pv1;
    auto issue = [&](int tt) {
        const int kk0 = tt * 64;
        pk0 = *(const uint4*)(Kb + (size_t)(kk0 + r0_) * D + c8_0);
        pv0 = *(const uint4*)(VTb + (size_t)r0_ * S + kk0 + c8_0);
        pk1 = *(const uint4*)(Kb + (size_t)(kk0 + r1_) * D + c8_1);
        pv1 = *(const uint4*)(VTb + (size_t)r1_ * S + kk0 + c8_1);
    };
    if (t0 < t1) issue(t0);

    for (int t = t0; t < t1; ++t) {
        const int k0 = t * 64;
        __syncthreads();                       // all waves done reading previous tile
        *(uint4*)(kt + r0_ * LTS + c8_0) = pk0;
        *(uint4*)(vt + r0_ * LTS + c8_0) = pv0;
        *(uint4*)(kt + r1_ * LTS + c8_1) = pk1;
        *(uint4*)(vt + r1_ * LTS + c8_1) = pv1;
        __syncthreads();
        if (t + 1 < t1) issue(t + 1);          // latency hides under compute below

        // ---- per 32-key half: S^T = K @ Q^T, exp, in-register transpose, PV ----
        #pragma unroll
        for (int ks = 0; ks < 2; ++ks) {
            unsigned w[2][2][2];   // [qg][ct_local][word]; word = key pair (even,odd)
            #pragma unroll
            for (int cl = 0; cl < 2; ++cl) {
                const int ct = ks * 2 + cl;
                Frag kf0, kf1;
                kf0.u4 = *(const uint4*)(kt + (ct * 16 + ln) * LTS + quad * 8);
                kf1.u4 = *(const uint4*)(kt + (ct * 16 + ln) * LTS + 32 + quad * 8);
                #pragma unroll
                for (int qg = 0; qg < 2; ++qg) {
                    f32x4 acc = {0.f, 0.f, 0.f, 0.f};
                    acc = __builtin_amdgcn_mfma_f32_16x16x32_f16(kf0.v, qf[qg][0].v, acc, 0, 0, 0);
                    acc = __builtin_amdgcn_mfma_f32_16x16x32_f16(kf1.v, qf[qg][1].v, acc, 0, 0, 0);
                    if (t >= tw) {   // diagonal (partial) or beyond (fully masked -> exp=0)
                        int keyb = k0 + ct * 16 + quad * 4;
                        int qrow = qrow_base + qg * 16 + ln;
                        #pragma unroll
                        for (int r = 0; r < 4; ++r)
                            if (keyb + r > qrow) acc[r] = -1e30f;
                    }
                    float p0 = ex2(acc[0]), p1 = ex2(acc[1]);
                    float p2 = ex2(acc[2]), p3 = ex2(acc[3]);
                    l_acc[qg] += (p0 + p1) + (p2 + p3);
#if __has_builtin(__builtin_amdgcn_cvt_pkrtz)
                    H2U c0, c1;                   // packed RTZ: 1 instr per 2 vals
                    c0.h = __builtin_amdgcn_cvt_pkrtz(p0, p1);
                    c1.h = __builtin_amdgcn_cvt_pkrtz(p2, p3);
                    w[qg][cl][0] = c0.u;
                    w[qg][cl][1] = c1.u;
#else
                    Pack4 pk;
                    pk.h[0] = (_Float16)p0; pk.h[1] = (_Float16)p1;
                    pk.h[2] = (_Float16)p2; pk.h[3] = (_Float16)p3;
                    w[qg][cl][0] = pk.u[0];
                    w[qg][cl][1] = pk.u[1];
#endif
                }
            }

            // in-register block transpose -> PV A-frags (no LDS round-trip)
            Frag pf[2];
            #pragma unroll
            for (int qg = 0; qg < 2; ++qg) {
                unsigned x0 = w[qg][0][0], y0 = w[qg][1][0];
                unsigned x1 = w[qg][0][1], y1 = w[qg][1][1];
#if __has_builtin(__builtin_amdgcn_permlane32_swap) && __has_builtin(__builtin_amdgcn_permlane16_swap)
                uint32x2 r;
                r = __builtin_amdgcn_permlane32_swap(x0, y0, false, false); x0 = r[0]; y0 = r[1];
                r = __builtin_amdgcn_permlane32_swap(x1, y1, false, false); x1 = r[0]; y1 = r[1];
                r = __builtin_amdgcn_permlane16_swap(x0, y0, false, false); x0 = r[0]; y0 = r[1];
                r = __builtin_amdgcn_permlane16_swap(x1, y1, false, false); x1 = r[0]; y1 = r[1];
#else
                asm volatile("s_nop 1\n\tv_permlane32_swap_b32 %0, %1\n\ts_nop 1"
                             : "+v"(x0), "+v"(y0));
                asm volatile("v_permlane32_swap_b32 %0, %1\n\ts_nop 1"
                             : "+v"(x1), "+v"(y1));
                asm volatile("v_permlane16_swap_b32 %0, %1\n\ts_nop 1"
                             : "+v"(x0), "+v"(y0));
                asm volatile("v_permlane16_swap_b32 %0, %1\n\ts_nop 1"
                             : "+v"(x1), "+v"(y1));
#endif
                pf[qg].u32[0] = x0; pf[qg].u32[1] = x1;   // A0,A1: keys quad*8+0..3
                pf[qg].u32[2] = y0; pf[qg].u32[3] = y1;   // A2,A3: keys quad*8+4..7
            }

            // ---- O += P @ V for this half; vf reused across both q-groups ----
            #pragma unroll
            for (int sub = 0; sub < 4; ++sub) {
                Frag vf;
                vf.u4 = *(const uint4*)(vt + (sub * 16 + ln) * LTS + ks * 32 + quad * 8);
                #pragma unroll
                for (int qg = 0; qg < 2; ++qg)
                    o[qg][sub] = __builtin_amdgcn_mfma_f32_16x16x32_f16(pf[qg].v, vf.v, o[qg][sub], 0, 0, 0);
            }
        }
    }

    // full denom per q (sum 4 quad-partials); lane ln holds denom of q = qg*16+ln
    float lf[2];
    #pragma unroll
    for (int qg = 0; qg < 2; ++qg) {
        float x = l_acc[qg];
        x += __shfl_xor(x, 16, 64);
        x += __shfl_xor(x, 32, 64);
        lf[qg] = x;
    }

    if (SPLIT) {
        // normalized f16 partial: Ohat = O/l (|Ohat| <= max|v|, f16-safe); merge = sum(l*Ohat)/sum(l)
        _Float16* OPb = OP + (size_t)(((b * 32 + J) * 4 + h)) * 8192;
        float* LPb = LP + (size_t)(((b * 32 + J) * 4 + h)) * 128;
        #pragma unroll
        for (int qg = 0; qg < 2; ++qg) {
            if (quad == 0) LPb[wave * 32 + qg * 16 + ln] = lf[qg];
            #pragma unroll
            for (int r = 0; r < 4; ++r) {
                float lrow = __shfl(lf[qg], quad * 4 + r, 64);
                float inv = (lrow > 0.f) ? (1.0f / lrow) : 0.f;  // guard: fully-masked/empty chunk
                #pragma unroll
                for (int sub = 0; sub < 4; ++sub)
                    OPb[(wave * 32 + qg * 16 + quad * 4 + r) * 64 + sub * 16 + ln] =
                        (_Float16)(o[qg][sub][r] * inv);
            }
        }
    } else {
        float* Ob = Out + (size_t)b * S * D;
        #pragma unroll
        for (int qg = 0; qg < 2; ++qg) {
            #pragma unroll
            for (int r = 0; r < 4; ++r) {
                float lrow = __shfl(lf[qg], quad * 4 + r, 64);
                float inv = 1.0f / lrow;
                #pragma unroll
                for (int sub = 0; sub < 4; ++sub)
                    Ob[(size_t)(qrow_base + qg * 16 + quad * 4 + r) * D + sub * 16 + ln] =
                        o[qg][sub][r] * inv;
            }
        }
    }
}

// split-K x4 over 128-q-row blocks: grid 2048 = 32 J x 4 quarters x 16 batches, LPT.
__global__ __launch_bounds__(256, 4)
void fattn_split_kernel(const float* __restrict__ Q, const _Float16* __restrict__ K16,
                        const _Float16* __restrict__ VT16,
                        _Float16* __restrict__ OP, float* __restrict__ LP) {
    const int bx = blockIdx.x;
    const int J = 31 - (bx >> 6);
    const int h = (bx >> 4) & 3;
    const int b = bx & 15;
    const int n  = 2 * J + 2;
    const int t0 = (h * n) >> 2;
    const int t1 = ((h + 1) * n) >> 2;
    fattn_body<1>(Q, K16, VT16, nullptr, OP, LP, b, J, t0, t1, h);
}

// fallback (ws too small): full range, direct store
__global__ __launch_bounds__(256, 4)
void fattn_kernel(const float* __restrict__ Q, const _Float16* __restrict__ K16,
                  const _Float16* __restrict__ VT16, float* __restrict__ Out) {
    const int bx = blockIdx.x;
    const int J = 31 - (bx >> 4);
    const int b = bx & 15;
    fattn_body<0>(Q, K16, VT16, Out, nullptr, nullptr, b, J, 0, 2 * J + 2, 0);
}

// merge: Out = sum_h(l_h * Ohat_h) / sum_h(l_h); one block per (b, J) tile of 128 rows
__global__ __launch_bounds__(256)
void reduce_kernel(const _Float16* __restrict__ OP, const float* __restrict__ LP,
                   float* __restrict__ Out) {
    const int rb = blockIdx.x;
    const int b  = rb & 15;
    const int J  = rb >> 4;
    const int tid = threadIdx.x;
    const _Float16* p = OP + (size_t)(b * 32 + J) * 4 * 8192;
    const float* l = LP + (size_t)(b * 32 + J) * 4 * 128;
    float* Ob = Out + (size_t)b * S * D + (size_t)J * 8192;
    #pragma unroll
    for (int i = 0; i < 4; ++i) {
        int e8 = tid + 256 * i;                 // half8 group index within 1024
        int q  = e8 >> 3;                       // q-row 0..127
        float lw[4], lsum = 0.f;
        #pragma unroll
        for (int hh = 0; hh < 4; ++hh) { lw[hh] = l[hh * 128 + q]; lsum += lw[hh]; }
        float inv = 1.0f / lsum;
        float acc[8] = {};
        #pragma unroll
        for (int hh = 0; hh < 4; ++hh) {
            half8 v = *(const half8*)(p + (size_t)hh * 8192 + e8 * 8);
            #pragma unroll
            for (int j = 0; j < 8; ++j) acc[j] += lw[hh] * (float)v[j];
        }
        float4 r0, r1;
        r0.x = acc[0]*inv; r0.y = acc[1]*inv; r0.z = acc[2]*inv; r0.w = acc[3]*inv;
        r1.x = acc[4]*inv; r1.y = acc[5]*inv; r1.z = acc[6]*inv; r1.w = acc[7]*inv;
        ((float4*)Ob)[2 * e8]     = r0;
        ((float4*)Ob)[2 * e8 + 1] = r1;
    }
}

extern "C" void kernel_launch(void* const* d_in, const int* in_sizes, int n_in,
                              void* d_out, int out_size, void* d_ws, size_t ws_size,
                              hipStream_t stream) {
    const float* Q = (const float*)d_in[0];
    const float* K = (const float*)d_in[1];
    const float* V = (const float*)d_in[2];
    float* O = (float*)d_out;

    const size_t prepBytes = (size_t)NB * S * D * 2;            // 8.39 MB each
    _Float16* K16  = (_Float16*)d_ws;
    _Float16* VT16 = (_Float16*)((char*)d_ws + prepBytes);

    const size_t opOff = 2 * prepBytes;                         // 16.78 MB
    const size_t opBytes = (size_t)NB * 32 * 4 * 8192 * 2;      // 33.55 MB (f16 partials)
    const size_t lpOff = opOff + opBytes;
    const size_t lpBytes = (size_t)NB * 32 * 4 * 128 * 4;       // 1.05 MB
    const size_t need = lpOff + lpBytes;                        // ~51.4 MB

    hipLaunchKernelGGL(prep_kernel, dim3(S / 64, NB), dim3(256), 0, stream, K, V, K16, VT16);

    if (ws_size >= need) {
        _Float16* OP = (_Float16*)((char*)d_ws + opOff);
        float* LP = (float*)((char*)d_ws + lpOff);
        hipLaunchKernelGGL(fattn_split_kernel, dim3(128 * NB), dim3(256), 0, stream,
                           Q, K16, VT16, OP, LP);
        hipLaunchKernelGGL(reduce_kernel, dim3(32 * NB), dim3(256), 0, stream, OP, LP, O);
    } else {
        hipLaunchKernelGGL(fattn_kernel, dim3(32 * NB), dim3(256), 0, stream, Q, K16, VT16, O);
    }
}